// Round 4
// baseline (340.803 us; speedup 1.0000x reference)
//
#include <hip/hip_runtime.h>
#include <math.h>
#include <float.h>

#define NNODES 50000
#define NEDGES 800000
#define NSCANB ((NNODES + 255) / 256)   // 196
// feature dims: in=hid=out=128, heads=4, head_dim=32

// ---------------- CSR build ----------------
__global__ __launch_bounds__(256) void hist_kernel(const int* __restrict__ dst,
                                                   int* __restrict__ deg) {
    int e = blockIdx.x * 256 + threadIdx.x;
    if (e < NEDGES) atomicAdd(&deg[dst[e]], 1);
}

__global__ __launch_bounds__(256) void scan1_kernel(const int* __restrict__ deg,
                                                    int* __restrict__ bsum) {
    int i = blockIdx.x * 256 + threadIdx.x;
    int t = threadIdx.x, lane = t & 63, w = t >> 6;
    int v = (i < NNODES) ? deg[i] : 0;
    int x = v;
#pragma unroll
    for (int off = 1; off < 64; off <<= 1) x += __shfl_xor(x, off);
    __shared__ int wtot[4];
    if (lane == 0) wtot[w] = x;
    __syncthreads();
    if (t == 0) bsum[blockIdx.x] = wtot[0] + wtot[1] + wtot[2] + wtot[3];
}

__global__ __launch_bounds__(256) void scan2_kernel(const int* __restrict__ bsum,
                                                    int* __restrict__ boff,
                                                    int* __restrict__ roff) {
    __shared__ int s[256];
    int t = threadIdx.x;
    int v = (t < NSCANB) ? bsum[t] : 0;
    s[t] = v;
    __syncthreads();
    for (int off = 1; off < 256; off <<= 1) {
        int y = (t >= off) ? s[t - off] : 0;
        __syncthreads();
        s[t] += y;
        __syncthreads();
    }
    if (t < NSCANB) boff[t] = s[t] - v;
    if (t == 255) roff[NNODES] = s[255];
}

__global__ __launch_bounds__(256) void scan3_kernel(const int* __restrict__ deg,
                                                    const int* __restrict__ boff,
                                                    int* __restrict__ roff,
                                                    int* __restrict__ cursor) {
    int i = blockIdx.x * 256 + threadIdx.x;
    int t = threadIdx.x, lane = t & 63, w = t >> 6;
    int v = (i < NNODES) ? deg[i] : 0;
    int x = v;
#pragma unroll
    for (int off = 1; off < 64; off <<= 1) {
        int y = __shfl_up(x, off, 64);
        if (lane >= off) x += y;
    }
    __shared__ int wtot[4];
    if (lane == 63) wtot[w] = x;
    __syncthreads();
    int wpre = 0;
#pragma unroll
    for (int j = 0; j < 4; ++j) if (j < w) wpre += wtot[j];
    int ex = boff[blockIdx.x] + wpre + x - v;
    if (i < NNODES) { roff[i] = ex; cursor[i] = ex; }
}

__global__ __launch_bounds__(256) void bucket_kernel(const int* __restrict__ src,
                                                     const int* __restrict__ dst,
                                                     int* __restrict__ cursor,
                                                     int* __restrict__ csr_src) {
    int e = blockIdx.x * 256 + threadIdx.x;
    if (e >= NEDGES) return;
    int d = dst[e];
    int pos = atomicAdd(&cursor[d], 1);
    csr_src[pos] = src[e];
}

// ---------------- GEMM + alpha: h = X@W ; alpha_s/d = <h, a_src/dst> -------
#define BM 64
#define BK 32
__global__ __launch_bounds__(256) void gemm_alpha_kernel(
    const float* __restrict__ X, const float* __restrict__ W,
    const float* __restrict__ avs, const float* __restrict__ avd,
    float* __restrict__ Hh, float* __restrict__ alpha_s, float* __restrict__ alpha_d,
    int nrows)
{
    __shared__ float Xs[BK][BM];
    __shared__ float Ws[BK][128];

    int t = threadIdx.x;
    int rg = t >> 4;
    int cg = t & 15;
    int row0 = rg * 4, col0 = cg * 8;
    int block_row = blockIdx.x * BM;

    float acc[4][8];
#pragma unroll
    for (int i = 0; i < 4; ++i)
#pragma unroll
        for (int j = 0; j < 8; ++j) acc[i][j] = 0.f;

    for (int k0 = 0; k0 < 128; k0 += BK) {
        {
            int r  = t >> 2;
            int kk = (t & 3) * 8;
            int grow = block_row + r;
            float4 v0 = make_float4(0,0,0,0), v1 = make_float4(0,0,0,0);
            if (grow < nrows) {
                const float* p = X + (size_t)grow * 128 + k0 + kk;
                v0 = *(const float4*)p;
                v1 = *(const float4*)(p + 4);
            }
            Xs[kk+0][r] = v0.x; Xs[kk+1][r] = v0.y; Xs[kk+2][r] = v0.z; Xs[kk+3][r] = v0.w;
            Xs[kk+4][r] = v1.x; Xs[kk+5][r] = v1.y; Xs[kk+6][r] = v1.z; Xs[kk+7][r] = v1.w;
        }
        {
            int kr = t >> 3;
            int cc = (t & 7) * 16;
            const float* p = W + (size_t)(k0 + kr) * 128 + cc;
            float4 w0 = ((const float4*)p)[0];
            float4 w1 = ((const float4*)p)[1];
            float4 w2 = ((const float4*)p)[2];
            float4 w3 = ((const float4*)p)[3];
            *(float4*)&Ws[kr][cc + 0]  = w0;
            *(float4*)&Ws[kr][cc + 4]  = w1;
            *(float4*)&Ws[kr][cc + 8]  = w2;
            *(float4*)&Ws[kr][cc + 12] = w3;
        }
        __syncthreads();
#pragma unroll
        for (int kk = 0; kk < BK; ++kk) {
            float4 a  = *(const float4*)&Xs[kk][row0];
            float4 w0 = *(const float4*)&Ws[kk][col0];
            float4 w1 = *(const float4*)&Ws[kk][col0 + 4];
            float av[4] = {a.x, a.y, a.z, a.w};
            float wv[8] = {w0.x, w0.y, w0.z, w0.w, w1.x, w1.y, w1.z, w1.w};
#pragma unroll
            for (int i = 0; i < 4; ++i)
#pragma unroll
                for (int j = 0; j < 8; ++j)
                    acc[i][j] = fmaf(av[i], wv[j], acc[i][j]);
        }
        __syncthreads();
    }

    int head = cg >> 2;
    const float* asrc = avs + head * 32 + (cg & 3) * 8;
    const float* adst = avd + head * 32 + (cg & 3) * 8;
#pragma unroll
    for (int i = 0; i < 4; ++i) {
        int grow = block_row + row0 + i;
        bool ok = (grow < nrows);
        if (ok) {
            float4 o0 = make_float4(acc[i][0], acc[i][1], acc[i][2], acc[i][3]);
            float4 o1 = make_float4(acc[i][4], acc[i][5], acc[i][6], acc[i][7]);
            *(float4*)&Hh[(size_t)grow * 128 + col0]     = o0;
            *(float4*)&Hh[(size_t)grow * 128 + col0 + 4] = o1;
        }
        float ps = 0.f, pd = 0.f;
#pragma unroll
        for (int j = 0; j < 8; ++j) {
            ps = fmaf(acc[i][j], asrc[j], ps);
            pd = fmaf(acc[i][j], adst[j], pd);
        }
        ps += __shfl_xor(ps, 1); ps += __shfl_xor(ps, 2);
        pd += __shfl_xor(pd, 1); pd += __shfl_xor(pd, 2);
        if (ok && (cg & 3) == 0) {
            alpha_s[grow * 4 + head] = ps;
            alpha_d[grow * 4 + head] = pd;
        }
    }
}

// ---------------- attention weights: ex[E][4], den[N][4] ----------------
// one wave per node; 16 lanes per head stride over the node's edges.
__global__ __launch_bounds__(256) void att_kernel(
    const int* __restrict__ csr_src, const int* __restrict__ roff,
    const float* __restrict__ alpha_s, const float* __restrict__ alpha_d,
    float* __restrict__ exb, float* __restrict__ den)
{
    int node = blockIdx.x * 4 + (threadIdx.x >> 6);
    if (node >= NNODES) return;
    int lane = threadIdx.x & 63;
    int hh = lane >> 4;          // head 0..3
    int j  = lane & 15;          // lane within head
    float ad = alpha_d[node * 4 + hh];
    int beg = roff[node], end = roff[node + 1];

    // pass 1: exact max
    float m = -INFINITY;
    for (int i = beg + j; i < end; i += 16) {
        int s = csr_src[i];
        float l = alpha_s[s * 4 + hh] + ad;
        l = (l >= 0.f) ? l : 0.2f * l;
        m = fmaxf(m, l);
    }
    m = fmaxf(m, __shfl_xor(m, 1));
    m = fmaxf(m, __shfl_xor(m, 2));
    m = fmaxf(m, __shfl_xor(m, 4));
    m = fmaxf(m, __shfl_xor(m, 8));

    // pass 2: exp + sum
    float sum = 0.f;
    for (int i = beg + j; i < end; i += 16) {
        int s = csr_src[i];
        float l = alpha_s[s * 4 + hh] + ad;
        l = (l >= 0.f) ? l : 0.2f * l;
        float ex = expf(l - m);
        exb[(size_t)i * 4 + hh] = ex;
        sum += ex;
    }
    sum += __shfl_xor(sum, 1);
    sum += __shfl_xor(sum, 2);
    sum += __shfl_xor(sum, 4);
    sum += __shfl_xor(sum, 8);
    if (j == 0) den[node * 4 + hh] = sum;
}

// ---------------- gather: out = elu(sum att*h[src] / den + b) --------------
// one wave per node; lane owns features 2*lane, 2*lane+1 (float2).
__global__ __launch_bounds__(256) void gather_kernel(
    const int* __restrict__ csr_src, const int* __restrict__ roff,
    const float* __restrict__ exb, const float* __restrict__ den,
    const float* __restrict__ hbuf, const float* __restrict__ b,
    float* __restrict__ out)
{
    int node = blockIdx.x * 4 + (threadIdx.x >> 6);
    if (node >= NNODES) return;
    int lane = threadIdx.x & 63;
    int hh = lane >> 4;          // head of features 2*lane, 2*lane+1
    int f = 2 * lane;
    int beg = roff[node], end = roff[node + 1];

    float ax = 0.f, ay = 0.f;
    int i = beg;
    for (; i + 1 < end; i += 2) {
        int s0 = csr_src[i];
        int s1 = csr_src[i + 1];
        float a0 = exb[(size_t)i * 4 + hh];
        float a1 = exb[(size_t)(i + 1) * 4 + hh];
        float2 h0 = *(const float2*)(hbuf + (size_t)s0 * 128 + f);
        float2 h1 = *(const float2*)(hbuf + (size_t)s1 * 128 + f);
        ax = fmaf(a0, h0.x, ax); ay = fmaf(a0, h0.y, ay);
        ax = fmaf(a1, h1.x, ax); ay = fmaf(a1, h1.y, ay);
    }
    if (i < end) {
        int s0 = csr_src[i];
        float a0 = exb[(size_t)i * 4 + hh];
        float2 h0 = *(const float2*)(hbuf + (size_t)s0 * 128 + f);
        ax = fmaf(a0, h0.x, ax); ay = fmaf(a0, h0.y, ay);
    }
    float rd = 1.f / fmaxf(den[node * 4 + hh], 1e-16f);
    float x0 = ax * rd + b[f];
    float x1 = ay * rd + b[f + 1];
    x0 = (x0 > 0.f) ? x0 : expm1f(x0);
    x1 = (x1 > 0.f) ? x1 : expm1f(x1);
    float2 o = make_float2(x0, x1);
    *(float2*)(out + (size_t)node * 128 + f) = o;
}

extern "C" void kernel_launch(void* const* d_in, const int* in_sizes, int n_in,
                              void* d_out, int out_size, void* d_ws, size_t ws_size,
                              hipStream_t stream) {
    const float* X    = (const float*)d_in[0];
    const int*   ei   = (const int*)d_in[1];
    const float* W0   = (const float*)d_in[2];
    const float* as0  = (const float*)d_in[3];
    const float* ad0  = (const float*)d_in[4];
    const float* b0   = (const float*)d_in[5];
    const float* W1   = (const float*)d_in[6];
    const float* as1  = (const float*)d_in[7];
    const float* ad1  = (const float*)d_in[8];
    const float* b1   = (const float*)d_in[9];

    const int* srcp = ei;            // edge_index[0]
    const int* dstp = ei + NEDGES;   // edge_index[1]

    float* ws = (float*)d_ws;
    float* h    = ws;                        // 6,400,000 floats
    float* hout = h    + 6400000;            // 6,400,000
    float* exb  = hout + 6400000;            // 3,200,000
    float* as_  = exb  + 3200000;            // 200,000
    float* ad_  = as_  + 200000;             // 200,000
    float* den  = ad_  + 200000;             // 200,000
    int*   deg     = (int*)(den + 200000);   // 50,000 ints
    int*   roff    = deg + 50000;            // 50,001
    int*   cursor  = roff + 50001;           // 50,000
    int*   csr_src = cursor + 50000;         // 800,000
    int*   bsum    = csr_src + 800000;       // 196
    int*   boff    = bsum + NSCANB;          // 196

    // ---- CSR build (by destination), layer-invariant ----
    hipMemsetAsync(deg, 0, NNODES * sizeof(int), stream);
    hist_kernel<<<(NEDGES + 255) / 256, 256, 0, stream>>>(dstp, deg);
    scan1_kernel<<<NSCANB, 256, 0, stream>>>(deg, bsum);
    scan2_kernel<<<1, 256, 0, stream>>>(bsum, boff, roff);
    scan3_kernel<<<NSCANB, 256, 0, stream>>>(deg, boff, roff, cursor);
    bucket_kernel<<<(NEDGES + 255) / 256, 256, 0, stream>>>(srcp, dstp, cursor, csr_src);

    const int NODE_BLOCKS = (NNODES + 3) / 4;   // 4 nodes (waves) per block

    for (int layer = 0; layer < 2; ++layer) {
        const float* Hin = layer ? hout : X;
        const float* W   = layer ? W1  : W0;
        const float* avs = layer ? as1 : as0;
        const float* avd = layer ? ad1 : ad0;
        const float* bv  = layer ? b1  : b0;
        float* outp      = layer ? (float*)d_out : hout;

        gemm_alpha_kernel<<<(NNODES + BM - 1) / BM, 256, 0, stream>>>(
            Hin, W, avs, avd, h, as_, ad_, NNODES);

        att_kernel<<<NODE_BLOCKS, 256, 0, stream>>>(
            csr_src, roff, as_, ad_, exb, den);

        gather_kernel<<<NODE_BLOCKS, 256, 0, stream>>>(
            csr_src, roff, exb, den, h, bv, outp);
    }
}

// Round 5
// 302.804 us; speedup vs baseline: 1.1255x; 1.1255x over previous
//
#include <hip/hip_runtime.h>
#include <math.h>
#include <float.h>

#define NNODES 50000
#define NEDGES 800000
#define NSCANB ((NNODES + 255) / 256)   // 196
#define CAP 128                          // max deg held in LDS (Poisson(16) max ~45)
// feature dims: in=hid=out=128, heads=4, head_dim=32

// ---------------- CSR build ----------------
__global__ __launch_bounds__(256) void hist_kernel(const int* __restrict__ dst,
                                                   int* __restrict__ deg) {
    int e = blockIdx.x * 256 + threadIdx.x;
    if (e < NEDGES) atomicAdd(&deg[dst[e]], 1);
}

__global__ __launch_bounds__(256) void scan1_kernel(const int* __restrict__ deg,
                                                    int* __restrict__ bsum) {
    int i = blockIdx.x * 256 + threadIdx.x;
    int t = threadIdx.x, lane = t & 63, w = t >> 6;
    int v = (i < NNODES) ? deg[i] : 0;
    int x = v;
#pragma unroll
    for (int off = 1; off < 64; off <<= 1) x += __shfl_xor(x, off);
    __shared__ int wtot[4];
    if (lane == 0) wtot[w] = x;
    __syncthreads();
    if (t == 0) bsum[blockIdx.x] = wtot[0] + wtot[1] + wtot[2] + wtot[3];
}

__global__ __launch_bounds__(256) void scan2_kernel(const int* __restrict__ bsum,
                                                    int* __restrict__ boff,
                                                    int* __restrict__ roff) {
    __shared__ int s[256];
    int t = threadIdx.x;
    int v = (t < NSCANB) ? bsum[t] : 0;
    s[t] = v;
    __syncthreads();
    for (int off = 1; off < 256; off <<= 1) {
        int y = (t >= off) ? s[t - off] : 0;
        __syncthreads();
        s[t] += y;
        __syncthreads();
    }
    if (t < NSCANB) boff[t] = s[t] - v;
    if (t == 255) roff[NNODES] = s[255];
}

__global__ __launch_bounds__(256) void scan3_kernel(const int* __restrict__ deg,
                                                    const int* __restrict__ boff,
                                                    int* __restrict__ roff,
                                                    int* __restrict__ cursor) {
    int i = blockIdx.x * 256 + threadIdx.x;
    int t = threadIdx.x, lane = t & 63, w = t >> 6;
    int v = (i < NNODES) ? deg[i] : 0;
    int x = v;
#pragma unroll
    for (int off = 1; off < 64; off <<= 1) {
        int y = __shfl_up(x, off, 64);
        if (lane >= off) x += y;
    }
    __shared__ int wtot[4];
    if (lane == 63) wtot[w] = x;
    __syncthreads();
    int wpre = 0;
#pragma unroll
    for (int j = 0; j < 4; ++j) if (j < w) wpre += wtot[j];
    int ex = boff[blockIdx.x] + wpre + x - v;
    if (i < NNODES) { roff[i] = ex; cursor[i] = ex; }
}

__global__ __launch_bounds__(256) void bucket_kernel(const int* __restrict__ src,
                                                     const int* __restrict__ dst,
                                                     int* __restrict__ cursor,
                                                     int* __restrict__ csr_src) {
    int e = blockIdx.x * 256 + threadIdx.x;
    if (e >= NEDGES) return;
    int d = dst[e];
    int pos = atomicAdd(&cursor[d], 1);
    csr_src[pos] = src[e];
}

// ---------------- GEMM + alpha: h = X@W ; alpha_s/d = <h, a_src/dst> -------
// 128-row tile, 256 threads, 8x8 acc per thread.
#define GBM 128
#define GBK 32
__global__ __launch_bounds__(256) void gemm_alpha_kernel(
    const float* __restrict__ X, const float* __restrict__ W,
    const float* __restrict__ avs, const float* __restrict__ avd,
    float* __restrict__ Hh, float* __restrict__ alpha_s, float* __restrict__ alpha_d,
    int nrows)
{
    __shared__ float Xs[GBK][GBM];   // transposed X tile: Xs[k][row], 16KB
    __shared__ float Ws[GBK][128];   // W tile: Ws[k][col], 16KB

    int t = threadIdx.x;
    int row0 = (t >> 4) * 8;         // 0..120
    int col0 = (t & 15) * 8;         // 0..120
    int block_row = blockIdx.x * GBM;

    float acc[8][8];
#pragma unroll
    for (int i = 0; i < 8; ++i)
#pragma unroll
        for (int j = 0; j < 8; ++j) acc[i][j] = 0.f;

    for (int k0 = 0; k0 < 128; k0 += GBK) {
        // stage X tile (128 rows x 32 k), transposed: thread loads 16 floats of row r
        {
            int r  = t >> 1;               // 0..127
            int kb = (t & 1) * 16;         // 0 or 16
            int grow = block_row + r;
            float4 v0 = make_float4(0,0,0,0), v1 = v0, v2 = v0, v3 = v0;
            if (grow < nrows) {
                const float* p = X + (size_t)grow * 128 + k0 + kb;
                v0 = ((const float4*)p)[0];
                v1 = ((const float4*)p)[1];
                v2 = ((const float4*)p)[2];
                v3 = ((const float4*)p)[3];
            }
            Xs[kb+ 0][r] = v0.x; Xs[kb+ 1][r] = v0.y; Xs[kb+ 2][r] = v0.z; Xs[kb+ 3][r] = v0.w;
            Xs[kb+ 4][r] = v1.x; Xs[kb+ 5][r] = v1.y; Xs[kb+ 6][r] = v1.z; Xs[kb+ 7][r] = v1.w;
            Xs[kb+ 8][r] = v2.x; Xs[kb+ 9][r] = v2.y; Xs[kb+10][r] = v2.z; Xs[kb+11][r] = v2.w;
            Xs[kb+12][r] = v3.x; Xs[kb+13][r] = v3.y; Xs[kb+14][r] = v3.z; Xs[kb+15][r] = v3.w;
        }
        // stage W tile (32 k x 128 cols)
        {
            int kr = t >> 3;               // 0..31
            int cc = (t & 7) * 16;         // 0..112
            const float* p = W + (size_t)(k0 + kr) * 128 + cc;
            float4 w0 = ((const float4*)p)[0];
            float4 w1 = ((const float4*)p)[1];
            float4 w2 = ((const float4*)p)[2];
            float4 w3 = ((const float4*)p)[3];
            *(float4*)&Ws[kr][cc + 0]  = w0;
            *(float4*)&Ws[kr][cc + 4]  = w1;
            *(float4*)&Ws[kr][cc + 8]  = w2;
            *(float4*)&Ws[kr][cc + 12] = w3;
        }
        __syncthreads();
#pragma unroll
        for (int kk = 0; kk < GBK; ++kk) {
            float4 a0 = *(const float4*)&Xs[kk][row0];
            float4 a1 = *(const float4*)&Xs[kk][row0 + 4];
            float4 w0 = *(const float4*)&Ws[kk][col0];
            float4 w1 = *(const float4*)&Ws[kk][col0 + 4];
            float av[8] = {a0.x, a0.y, a0.z, a0.w, a1.x, a1.y, a1.z, a1.w};
            float wv[8] = {w0.x, w0.y, w0.z, w0.w, w1.x, w1.y, w1.z, w1.w};
#pragma unroll
            for (int i = 0; i < 8; ++i)
#pragma unroll
                for (int j = 0; j < 8; ++j)
                    acc[i][j] = fmaf(av[i], wv[j], acc[i][j]);
        }
        __syncthreads();
    }

    int cg = t & 15;
    int head = cg >> 2;                       // col0/32
    const float* asrc = avs + head * 32 + (cg & 3) * 8;
    const float* adst = avd + head * 32 + (cg & 3) * 8;
#pragma unroll
    for (int i = 0; i < 8; ++i) {
        int grow = block_row + row0 + i;
        bool ok = (grow < nrows);
        if (ok) {
            float4 o0 = make_float4(acc[i][0], acc[i][1], acc[i][2], acc[i][3]);
            float4 o1 = make_float4(acc[i][4], acc[i][5], acc[i][6], acc[i][7]);
            *(float4*)&Hh[(size_t)grow * 128 + col0]     = o0;
            *(float4*)&Hh[(size_t)grow * 128 + col0 + 4] = o1;
        }
        float ps = 0.f, pd = 0.f;
#pragma unroll
        for (int j = 0; j < 8; ++j) {
            ps = fmaf(acc[i][j], asrc[j], ps);
            pd = fmaf(acc[i][j], adst[j], pd);
        }
        ps += __shfl_xor(ps, 1); ps += __shfl_xor(ps, 2);
        pd += __shfl_xor(pd, 1); pd += __shfl_xor(pd, 2);
        if (ok && (cg & 3) == 0) {
            alpha_s[grow * 4 + head] = ps;
            alpha_d[grow * 4 + head] = pd;
        }
    }
}

// ------- fused attention + gather: out = elu(sum att*h[src] / den + b) -----
// one wave per node. No max-shift: logits are O(+-6), exp(l) is fp32-safe and
// softmax is shift-invariant.
// pass 1: lanes (head hh = lane>>4, j = lane&15) stride edges; ex -> LDS,
//         denom via shfl reduce (kept in register).
// pass 2: lane owns features 2*lane, 2*lane+1; coalesced 512B row gathers.
__global__ __launch_bounds__(256) void att_gather_kernel(
    const int* __restrict__ csr_src, const int* __restrict__ roff,
    const float* __restrict__ alpha_s, const float* __restrict__ alpha_d,
    const float* __restrict__ hbuf, const float* __restrict__ b,
    float* __restrict__ out)
{
    __shared__ float lds_ex[4][CAP * 4];
    int w = threadIdx.x >> 6;
    int node = blockIdx.x * 4 + w;
    if (node >= NNODES) return;
    int lane = threadIdx.x & 63;
    int hh = lane >> 4;                 // head (same for pass 1 and pass 2)
    int j  = lane & 15;
    int beg = roff[node], end = roff[node + 1];
    int deg = end - beg;
    bool fits = (deg <= CAP);
    float ad = alpha_d[node * 4 + hh];

    // pass 1: ex = exp(leakyrelu(alpha_s[src] + ad)), denom
    float sum = 0.f;
    for (int i = beg + j; i < end; i += 16) {
        int s = csr_src[i];
        float l = alpha_s[s * 4 + hh] + ad;
        l = (l >= 0.f) ? l : 0.2f * l;
        float ex = __expf(l);
        if (fits) lds_ex[w][(i - beg) * 4 + hh] = ex;
        sum += ex;
    }
    sum += __shfl_xor(sum, 1);
    sum += __shfl_xor(sum, 2);
    sum += __shfl_xor(sum, 4);
    sum += __shfl_xor(sum, 8);          // all 16 lanes of this head hold denom
    float rd = 1.f / fmaxf(sum, 1e-16f);

    // pass 2: weighted gather, lane owns features f, f+1
    int f = lane * 2;
    float ax = 0.f, ay = 0.f;
    if (fits) {
        int i = beg;
        for (; i + 1 < end; i += 2) {
            int s0 = csr_src[i];
            int s1 = csr_src[i + 1];
            float a0 = lds_ex[w][(i - beg) * 4 + hh];
            float a1 = lds_ex[w][(i + 1 - beg) * 4 + hh];
            float2 h0 = *(const float2*)(hbuf + (size_t)s0 * 128 + f);
            float2 h1 = *(const float2*)(hbuf + (size_t)s1 * 128 + f);
            ax = fmaf(a0, h0.x, ax); ay = fmaf(a0, h0.y, ay);
            ax = fmaf(a1, h1.x, ax); ay = fmaf(a1, h1.y, ay);
        }
        if (i < end) {
            int s0 = csr_src[i];
            float a0 = lds_ex[w][(i - beg) * 4 + hh];
            float2 h0 = *(const float2*)(hbuf + (size_t)s0 * 128 + f);
            ax = fmaf(a0, h0.x, ax); ay = fmaf(a0, h0.y, ay);
        }
    } else {
        // rare giant node: recompute ex per edge (no memory handoff needed)
        for (int i = beg; i < end; ++i) {
            int s = csr_src[i];
            float l = alpha_s[s * 4 + hh] + ad;
            l = (l >= 0.f) ? l : 0.2f * l;
            float a = __expf(l);
            float2 hv = *(const float2*)(hbuf + (size_t)s * 128 + f);
            ax = fmaf(a, hv.x, ax); ay = fmaf(a, hv.y, ay);
        }
    }
    float x0 = ax * rd + b[f];
    float x1 = ay * rd + b[f + 1];
    x0 = (x0 > 0.f) ? x0 : expm1f(x0);
    x1 = (x1 > 0.f) ? x1 : expm1f(x1);
    *(float2*)(out + (size_t)node * 128 + f) = make_float2(x0, x1);
}

extern "C" void kernel_launch(void* const* d_in, const int* in_sizes, int n_in,
                              void* d_out, int out_size, void* d_ws, size_t ws_size,
                              hipStream_t stream) {
    const float* X    = (const float*)d_in[0];
    const int*   ei   = (const int*)d_in[1];
    const float* W0   = (const float*)d_in[2];
    const float* as0  = (const float*)d_in[3];
    const float* ad0  = (const float*)d_in[4];
    const float* b0   = (const float*)d_in[5];
    const float* W1   = (const float*)d_in[6];
    const float* as1  = (const float*)d_in[7];
    const float* ad1  = (const float*)d_in[8];
    const float* b1   = (const float*)d_in[9];

    const int* srcp = ei;            // edge_index[0]
    const int* dstp = ei + NEDGES;   // edge_index[1]

    float* ws = (float*)d_ws;
    float* h    = ws;                        // 6,400,000 floats
    float* hout = h    + 6400000;            // 6,400,000
    float* as_  = hout + 6400000;            // 200,000
    float* ad_  = as_  + 200000;             // 200,000
    int*   deg     = (int*)(ad_ + 200000);   // 50,000 ints
    int*   roff    = deg + 50000;            // 50,001
    int*   cursor  = roff + 50001;           // 50,000
    int*   csr_src = cursor + 50000;         // 800,000
    int*   bsum    = csr_src + 800000;       // 196
    int*   boff    = bsum + NSCANB;          // 196

    // ---- CSR build (by destination), layer-invariant ----
    hipMemsetAsync(deg, 0, NNODES * sizeof(int), stream);
    hist_kernel<<<(NEDGES + 255) / 256, 256, 0, stream>>>(dstp, deg);
    scan1_kernel<<<NSCANB, 256, 0, stream>>>(deg, bsum);
    scan2_kernel<<<1, 256, 0, stream>>>(bsum, boff, roff);
    scan3_kernel<<<NSCANB, 256, 0, stream>>>(deg, boff, roff, cursor);
    bucket_kernel<<<(NEDGES + 255) / 256, 256, 0, stream>>>(srcp, dstp, cursor, csr_src);

    const int NODE_BLOCKS = (NNODES + 3) / 4;   // 4 nodes (waves) per block

    for (int layer = 0; layer < 2; ++layer) {
        const float* Hin = layer ? hout : X;
        const float* W   = layer ? W1  : W0;
        const float* avs = layer ? as1 : as0;
        const float* avd = layer ? ad1 : ad0;
        const float* bv  = layer ? b1  : b0;
        float* outp      = layer ? (float*)d_out : hout;

        gemm_alpha_kernel<<<(NNODES + GBM - 1) / GBM, 256, 0, stream>>>(
            Hin, W, avs, avd, h, as_, ad_, NNODES);

        att_gather_kernel<<<NODE_BLOCKS, 256, 0, stream>>>(
            csr_src, roff, as_, ad_, h, bv, outp);
    }
}

// Round 6
// 289.530 us; speedup vs baseline: 1.1771x; 1.0458x over previous
//
#include <hip/hip_runtime.h>
#include <math.h>
#include <float.h>

#define NNODES 50000
#define NEDGES 800000
#define NSCANB ((NNODES + 255) / 256)   // 196
#define CAP 64                           // max deg held in LDS (Poisson(16) max ~50)
// feature dims: in=hid=out=128, heads=4, head_dim=32

// ---------------- CSR build ----------------
__global__ __launch_bounds__(256) void hist_kernel(const int* __restrict__ dst,
                                                   int* __restrict__ deg) {
    int e = blockIdx.x * 256 + threadIdx.x;
    if (e < NEDGES) atomicAdd(&deg[dst[e]], 1);
}

__global__ __launch_bounds__(256) void scan1_kernel(const int* __restrict__ deg,
                                                    int* __restrict__ bsum) {
    int i = blockIdx.x * 256 + threadIdx.x;
    int t = threadIdx.x, lane = t & 63, w = t >> 6;
    int v = (i < NNODES) ? deg[i] : 0;
    int x = v;
#pragma unroll
    for (int off = 1; off < 64; off <<= 1) x += __shfl_xor(x, off);
    __shared__ int wtot[4];
    if (lane == 0) wtot[w] = x;
    __syncthreads();
    if (t == 0) bsum[blockIdx.x] = wtot[0] + wtot[1] + wtot[2] + wtot[3];
}

__global__ __launch_bounds__(256) void scan2_kernel(const int* __restrict__ bsum,
                                                    int* __restrict__ boff,
                                                    int* __restrict__ roff) {
    __shared__ int s[256];
    int t = threadIdx.x;
    int v = (t < NSCANB) ? bsum[t] : 0;
    s[t] = v;
    __syncthreads();
    for (int off = 1; off < 256; off <<= 1) {
        int y = (t >= off) ? s[t - off] : 0;
        __syncthreads();
        s[t] += y;
        __syncthreads();
    }
    if (t < NSCANB) boff[t] = s[t] - v;
    if (t == 255) roff[NNODES] = s[255];
}

__global__ __launch_bounds__(256) void scan3_kernel(const int* __restrict__ deg,
                                                    const int* __restrict__ boff,
                                                    int* __restrict__ roff,
                                                    int* __restrict__ cursor) {
    int i = blockIdx.x * 256 + threadIdx.x;
    int t = threadIdx.x, lane = t & 63, w = t >> 6;
    int v = (i < NNODES) ? deg[i] : 0;
    int x = v;
#pragma unroll
    for (int off = 1; off < 64; off <<= 1) {
        int y = __shfl_up(x, off, 64);
        if (lane >= off) x += y;
    }
    __shared__ int wtot[4];
    if (lane == 63) wtot[w] = x;
    __syncthreads();
    int wpre = 0;
#pragma unroll
    for (int j = 0; j < 4; ++j) if (j < w) wpre += wtot[j];
    int ex = boff[blockIdx.x] + wpre + x - v;
    if (i < NNODES) { roff[i] = ex; cursor[i] = ex; }
}

__global__ __launch_bounds__(256) void bucket_kernel(const int* __restrict__ src,
                                                     const int* __restrict__ dst,
                                                     int* __restrict__ cursor,
                                                     int* __restrict__ csr_src) {
    int e = blockIdx.x * 256 + threadIdx.x;
    if (e >= NEDGES) return;
    int d = dst[e];
    int pos = atomicAdd(&cursor[d], 1);
    csr_src[pos] = src[e];
}

// ---------------- GEMM + alpha: h = X@W ; alpha_s/d = <h, a_src/dst> -------
// 128-row tile, 256 threads, 8x8 acc per thread.
#define GBM 128
#define GBK 32
__global__ __launch_bounds__(256) void gemm_alpha_kernel(
    const float* __restrict__ X, const float* __restrict__ W,
    const float* __restrict__ avs, const float* __restrict__ avd,
    float* __restrict__ Hh, float* __restrict__ alpha_s, float* __restrict__ alpha_d,
    int nrows)
{
    __shared__ float Xs[GBK][GBM];   // transposed X tile: Xs[k][row], 16KB
    __shared__ float Ws[GBK][128];   // W tile: Ws[k][col], 16KB

    int t = threadIdx.x;
    int row0 = (t >> 4) * 8;         // 0..120
    int col0 = (t & 15) * 8;         // 0..120
    int block_row = blockIdx.x * GBM;

    float acc[8][8];
#pragma unroll
    for (int i = 0; i < 8; ++i)
#pragma unroll
        for (int j = 0; j < 8; ++j) acc[i][j] = 0.f;

    for (int k0 = 0; k0 < 128; k0 += GBK) {
        {
            int r  = t >> 1;               // 0..127
            int kb = (t & 1) * 16;         // 0 or 16
            int grow = block_row + r;
            float4 v0 = make_float4(0,0,0,0), v1 = v0, v2 = v0, v3 = v0;
            if (grow < nrows) {
                const float* p = X + (size_t)grow * 128 + k0 + kb;
                v0 = ((const float4*)p)[0];
                v1 = ((const float4*)p)[1];
                v2 = ((const float4*)p)[2];
                v3 = ((const float4*)p)[3];
            }
            Xs[kb+ 0][r] = v0.x; Xs[kb+ 1][r] = v0.y; Xs[kb+ 2][r] = v0.z; Xs[kb+ 3][r] = v0.w;
            Xs[kb+ 4][r] = v1.x; Xs[kb+ 5][r] = v1.y; Xs[kb+ 6][r] = v1.z; Xs[kb+ 7][r] = v1.w;
            Xs[kb+ 8][r] = v2.x; Xs[kb+ 9][r] = v2.y; Xs[kb+10][r] = v2.z; Xs[kb+11][r] = v2.w;
            Xs[kb+12][r] = v3.x; Xs[kb+13][r] = v3.y; Xs[kb+14][r] = v3.z; Xs[kb+15][r] = v3.w;
        }
        {
            int kr = t >> 3;               // 0..31
            int cc = (t & 7) * 16;         // 0..112
            const float* p = W + (size_t)(k0 + kr) * 128 + cc;
            float4 w0 = ((const float4*)p)[0];
            float4 w1 = ((const float4*)p)[1];
            float4 w2 = ((const float4*)p)[2];
            float4 w3 = ((const float4*)p)[3];
            *(float4*)&Ws[kr][cc + 0]  = w0;
            *(float4*)&Ws[kr][cc + 4]  = w1;
            *(float4*)&Ws[kr][cc + 8]  = w2;
            *(float4*)&Ws[kr][cc + 12] = w3;
        }
        __syncthreads();
#pragma unroll
        for (int kk = 0; kk < GBK; ++kk) {
            float4 a0 = *(const float4*)&Xs[kk][row0];
            float4 a1 = *(const float4*)&Xs[kk][row0 + 4];
            float4 w0 = *(const float4*)&Ws[kk][col0];
            float4 w1 = *(const float4*)&Ws[kk][col0 + 4];
            float av[8] = {a0.x, a0.y, a0.z, a0.w, a1.x, a1.y, a1.z, a1.w};
            float wv[8] = {w0.x, w0.y, w0.z, w0.w, w1.x, w1.y, w1.z, w1.w};
#pragma unroll
            for (int i = 0; i < 8; ++i)
#pragma unroll
                for (int j = 0; j < 8; ++j)
                    acc[i][j] = fmaf(av[i], wv[j], acc[i][j]);
        }
        __syncthreads();
    }

    int cg = t & 15;
    int head = cg >> 2;                       // col0/32
    const float* asrc = avs + head * 32 + (cg & 3) * 8;
    const float* adst = avd + head * 32 + (cg & 3) * 8;
#pragma unroll
    for (int i = 0; i < 8; ++i) {
        int grow = block_row + row0 + i;
        bool ok = (grow < nrows);
        if (ok) {
            float4 o0 = make_float4(acc[i][0], acc[i][1], acc[i][2], acc[i][3]);
            float4 o1 = make_float4(acc[i][4], acc[i][5], acc[i][6], acc[i][7]);
            *(float4*)&Hh[(size_t)grow * 128 + col0]     = o0;
            *(float4*)&Hh[(size_t)grow * 128 + col0 + 4] = o1;
        }
        float ps = 0.f, pd = 0.f;
#pragma unroll
        for (int j = 0; j < 8; ++j) {
            ps = fmaf(acc[i][j], asrc[j], ps);
            pd = fmaf(acc[i][j], adst[j], pd);
        }
        ps += __shfl_xor(ps, 1); ps += __shfl_xor(ps, 2);
        pd += __shfl_xor(pd, 1); pd += __shfl_xor(pd, 2);
        if (ok && (cg & 3) == 0) {
            alpha_s[grow * 4 + head] = ps;
            alpha_d[grow * 4 + head] = pd;
        }
    }
}

// ------- fused attention + gather: out = elu(sum att*h[src] / den + b) -----
// one wave per node. No max-shift (logits O(+-6), exp fp32-safe, softmax
// shift-invariant).
// pass 1: head hh = lane>>4, j = lane&15 stride edges; ex -> LDS, denom via
//         shfl reduce.
// pass 2: half = lane>>5 processes edges beg+half, beg+half+2, ...; lane owns
//         features q*4..q*4+3 (q = lane&31): 32 lanes x 16B = full 512B row.
//         Halves combined via __shfl_xor(.,32).
__global__ __launch_bounds__(256) void att_gather_kernel(
    const int* __restrict__ csr_src, const int* __restrict__ roff,
    const float* __restrict__ alpha_s, const float* __restrict__ alpha_d,
    const float* __restrict__ hbuf, const float* __restrict__ b,
    float* __restrict__ out)
{
    __shared__ float lds_ex[4][CAP * 4];
    int w = threadIdx.x >> 6;
    int node = blockIdx.x * 4 + w;
    if (node >= NNODES) return;
    int lane = threadIdx.x & 63;
    int hh = lane >> 4;                 // pass-1 head
    int j  = lane & 15;
    int beg = roff[node], end = roff[node + 1];
    int deg = end - beg;
    bool fits = (deg <= CAP);
    float ad = alpha_d[node * 4 + hh];

    // pass 1: ex = exp(leakyrelu(alpha_s[src] + ad)), denom per head
    float sum = 0.f;
    for (int i = beg + j; i < end; i += 16) {
        int s = csr_src[i];
        float l = alpha_s[s * 4 + hh] + ad;
        l = (l >= 0.f) ? l : 0.2f * l;
        float ex = __expf(l);
        if (fits) lds_ex[w][(i - beg) * 4 + hh] = ex;
        sum += ex;
    }
    sum += __shfl_xor(sum, 1);
    sum += __shfl_xor(sum, 2);
    sum += __shfl_xor(sum, 4);
    sum += __shfl_xor(sum, 8);          // all 16 lanes of head hh hold denom

    // pass 2 lane mapping
    int half = lane >> 5;               // which edge parity this lane handles
    int q    = lane & 31;               // lane within half
    int f    = q * 4;                   // features f..f+3
    int hh2  = q >> 3;                  // head owning features f..f+3
    float sum2 = __shfl(sum, hh2 << 4); // denom for head hh2
    float rd = 1.f / fmaxf(sum2, 1e-16f);

    float4 a4 = make_float4(0.f, 0.f, 0.f, 0.f);
    if (fits) {
        int i = beg + half;
        for (; i + 2 < end; i += 4) {   // 2 independent edges per iter
            int s0 = csr_src[i];
            int s1 = csr_src[i + 2];
            float e0 = lds_ex[w][(i - beg) * 4 + hh2];
            float e1 = lds_ex[w][(i + 2 - beg) * 4 + hh2];
            float4 h0 = *(const float4*)(hbuf + (size_t)s0 * 128 + f);
            float4 h1 = *(const float4*)(hbuf + (size_t)s1 * 128 + f);
            a4.x = fmaf(e0, h0.x, a4.x); a4.y = fmaf(e0, h0.y, a4.y);
            a4.z = fmaf(e0, h0.z, a4.z); a4.w = fmaf(e0, h0.w, a4.w);
            a4.x = fmaf(e1, h1.x, a4.x); a4.y = fmaf(e1, h1.y, a4.y);
            a4.z = fmaf(e1, h1.z, a4.z); a4.w = fmaf(e1, h1.w, a4.w);
        }
        if (i < end) {
            int s0 = csr_src[i];
            float e0 = lds_ex[w][(i - beg) * 4 + hh2];
            float4 h0 = *(const float4*)(hbuf + (size_t)s0 * 128 + f);
            a4.x = fmaf(e0, h0.x, a4.x); a4.y = fmaf(e0, h0.y, a4.y);
            a4.z = fmaf(e0, h0.z, a4.z); a4.w = fmaf(e0, h0.w, a4.w);
        }
    } else {
        // rare giant node: recompute ex per edge
        float ad2 = __shfl(ad, hh2 << 4);
        for (int i = beg + half; i < end; i += 2) {
            int s = csr_src[i];
            float l = alpha_s[s * 4 + hh2] + ad2;
            l = (l >= 0.f) ? l : 0.2f * l;
            float a = __expf(l);
            float4 hv = *(const float4*)(hbuf + (size_t)s * 128 + f);
            a4.x = fmaf(a, hv.x, a4.x); a4.y = fmaf(a, hv.y, a4.y);
            a4.z = fmaf(a, hv.z, a4.z); a4.w = fmaf(a, hv.w, a4.w);
        }
    }
    // combine even/odd halves (lane l and l+32 hold the same features)
    a4.x += __shfl_xor(a4.x, 32);
    a4.y += __shfl_xor(a4.y, 32);
    a4.z += __shfl_xor(a4.z, 32);
    a4.w += __shfl_xor(a4.w, 32);

    if (half == 0) {
        float4 bv = *(const float4*)(b + f);
        float x0 = a4.x * rd + bv.x;
        float x1 = a4.y * rd + bv.y;
        float x2 = a4.z * rd + bv.z;
        float x3 = a4.w * rd + bv.w;
        x0 = (x0 > 0.f) ? x0 : expm1f(x0);
        x1 = (x1 > 0.f) ? x1 : expm1f(x1);
        x2 = (x2 > 0.f) ? x2 : expm1f(x2);
        x3 = (x3 > 0.f) ? x3 : expm1f(x3);
        *(float4*)(out + (size_t)node * 128 + f) = make_float4(x0, x1, x2, x3);
    }
}

extern "C" void kernel_launch(void* const* d_in, const int* in_sizes, int n_in,
                              void* d_out, int out_size, void* d_ws, size_t ws_size,
                              hipStream_t stream) {
    const float* X    = (const float*)d_in[0];
    const int*   ei   = (const int*)d_in[1];
    const float* W0   = (const float*)d_in[2];
    const float* as0  = (const float*)d_in[3];
    const float* ad0  = (const float*)d_in[4];
    const float* b0   = (const float*)d_in[5];
    const float* W1   = (const float*)d_in[6];
    const float* as1  = (const float*)d_in[7];
    const float* ad1  = (const float*)d_in[8];
    const float* b1   = (const float*)d_in[9];

    const int* srcp = ei;            // edge_index[0]
    const int* dstp = ei + NEDGES;   // edge_index[1]

    float* ws = (float*)d_ws;
    float* h    = ws;                        // 6,400,000 floats
    float* hout = h    + 6400000;            // 6,400,000
    float* as_  = hout + 6400000;            // 200,000
    float* ad_  = as_  + 200000;             // 200,000
    int*   deg     = (int*)(ad_ + 200000);   // 50,000 ints
    int*   roff    = deg + 50000;            // 50,001
    int*   cursor  = roff + 50001;           // 50,000
    int*   csr_src = cursor + 50000;         // 800,000
    int*   bsum    = csr_src + 800000;       // 196
    int*   boff    = bsum + NSCANB;          // 196

    // ---- CSR build (by destination), layer-invariant ----
    hipMemsetAsync(deg, 0, NNODES * sizeof(int), stream);
    hist_kernel<<<(NEDGES + 255) / 256, 256, 0, stream>>>(dstp, deg);
    scan1_kernel<<<NSCANB, 256, 0, stream>>>(deg, bsum);
    scan2_kernel<<<1, 256, 0, stream>>>(bsum, boff, roff);
    scan3_kernel<<<NSCANB, 256, 0, stream>>>(deg, boff, roff, cursor);
    bucket_kernel<<<(NEDGES + 255) / 256, 256, 0, stream>>>(srcp, dstp, cursor, csr_src);

    const int NODE_BLOCKS = (NNODES + 3) / 4;   // 4 nodes (waves) per block

    for (int layer = 0; layer < 2; ++layer) {
        const float* Hin = layer ? hout : X;
        const float* W   = layer ? W1  : W0;
        const float* avs = layer ? as1 : as0;
        const float* avd = layer ? ad1 : ad0;
        const float* bv  = layer ? b1  : b0;
        float* outp      = layer ? (float*)d_out : hout;

        gemm_alpha_kernel<<<(NNODES + GBM - 1) / GBM, 256, 0, stream>>>(
            Hin, W, avs, avd, h, as_, ad_, NNODES);

        att_gather_kernel<<<NODE_BLOCKS, 256, 0, stream>>>(
            csr_src, roff, as_, ad_, h, bv, outp);
    }
}

// Round 7
// 284.920 us; speedup vs baseline: 1.1961x; 1.0162x over previous
//
#include <hip/hip_runtime.h>
#include <math.h>
#include <float.h>

#define NNODES 50000
#define NEDGES 800000
#define NSCANB ((NNODES + 255) / 256)   // 196
// feature dims: in=hid=out=128, heads=4, head_dim=32

// ---------------- CSR build ----------------
__global__ __launch_bounds__(256) void hist_kernel(const int* __restrict__ dst,
                                                   int* __restrict__ deg) {
    int e = blockIdx.x * 256 + threadIdx.x;
    if (e < NEDGES) atomicAdd(&deg[dst[e]], 1);
}

__global__ __launch_bounds__(256) void scan1_kernel(const int* __restrict__ deg,
                                                    int* __restrict__ bsum) {
    int i = blockIdx.x * 256 + threadIdx.x;
    int t = threadIdx.x, lane = t & 63, w = t >> 6;
    int v = (i < NNODES) ? deg[i] : 0;
    int x = v;
#pragma unroll
    for (int off = 1; off < 64; off <<= 1) x += __shfl_xor(x, off);
    __shared__ int wtot[4];
    if (lane == 0) wtot[w] = x;
    __syncthreads();
    if (t == 0) bsum[blockIdx.x] = wtot[0] + wtot[1] + wtot[2] + wtot[3];
}

__global__ __launch_bounds__(256) void scan2_kernel(const int* __restrict__ bsum,
                                                    int* __restrict__ boff,
                                                    int* __restrict__ roff) {
    __shared__ int s[256];
    int t = threadIdx.x;
    int v = (t < NSCANB) ? bsum[t] : 0;
    s[t] = v;
    __syncthreads();
    for (int off = 1; off < 256; off <<= 1) {
        int y = (t >= off) ? s[t - off] : 0;
        __syncthreads();
        s[t] += y;
        __syncthreads();
    }
    if (t < NSCANB) boff[t] = s[t] - v;
    if (t == 255) roff[NNODES] = s[255];
}

__global__ __launch_bounds__(256) void scan3_kernel(const int* __restrict__ deg,
                                                    const int* __restrict__ boff,
                                                    int* __restrict__ roff,
                                                    int* __restrict__ cursor) {
    int i = blockIdx.x * 256 + threadIdx.x;
    int t = threadIdx.x, lane = t & 63, w = t >> 6;
    int v = (i < NNODES) ? deg[i] : 0;
    int x = v;
#pragma unroll
    for (int off = 1; off < 64; off <<= 1) {
        int y = __shfl_up(x, off, 64);
        if (lane >= off) x += y;
    }
    __shared__ int wtot[4];
    if (lane == 63) wtot[w] = x;
    __syncthreads();
    int wpre = 0;
#pragma unroll
    for (int j = 0; j < 4; ++j) if (j < w) wpre += wtot[j];
    int ex = boff[blockIdx.x] + wpre + x - v;
    if (i < NNODES) { roff[i] = ex; cursor[i] = ex; }
}

__global__ __launch_bounds__(256) void bucket_kernel(const int* __restrict__ src,
                                                     const int* __restrict__ dst,
                                                     int* __restrict__ cursor,
                                                     int* __restrict__ csr_src) {
    int e = blockIdx.x * 256 + threadIdx.x;
    if (e >= NEDGES) return;
    int d = dst[e];
    int pos = atomicAdd(&cursor[d], 1);
    csr_src[pos] = src[e];
}

// ---------------- GEMM + alpha: h = X@W ; alpha_s/d = <h, a_src/dst> -------
// 128-row tile, 256 threads, 8x8 acc per thread.
#define GBM 128
#define GBK 32
__global__ __launch_bounds__(256) void gemm_alpha_kernel(
    const float* __restrict__ X, const float* __restrict__ W,
    const float* __restrict__ avs, const float* __restrict__ avd,
    float* __restrict__ Hh, float* __restrict__ alpha_s, float* __restrict__ alpha_d,
    int nrows)
{
    __shared__ float Xs[GBK][GBM];   // transposed X tile: Xs[k][row], 16KB
    __shared__ float Ws[GBK][128];   // W tile: Ws[k][col], 16KB

    int t = threadIdx.x;
    int row0 = (t >> 4) * 8;         // 0..120
    int col0 = (t & 15) * 8;         // 0..120
    int block_row = blockIdx.x * GBM;

    float acc[8][8];
#pragma unroll
    for (int i = 0; i < 8; ++i)
#pragma unroll
        for (int j = 0; j < 8; ++j) acc[i][j] = 0.f;

    for (int k0 = 0; k0 < 128; k0 += GBK) {
        {
            int r  = t >> 1;               // 0..127
            int kb = (t & 1) * 16;         // 0 or 16
            int grow = block_row + r;
            float4 v0 = make_float4(0,0,0,0), v1 = v0, v2 = v0, v3 = v0;
            if (grow < nrows) {
                const float* p = X + (size_t)grow * 128 + k0 + kb;
                v0 = ((const float4*)p)[0];
                v1 = ((const float4*)p)[1];
                v2 = ((const float4*)p)[2];
                v3 = ((const float4*)p)[3];
            }
            Xs[kb+ 0][r] = v0.x; Xs[kb+ 1][r] = v0.y; Xs[kb+ 2][r] = v0.z; Xs[kb+ 3][r] = v0.w;
            Xs[kb+ 4][r] = v1.x; Xs[kb+ 5][r] = v1.y; Xs[kb+ 6][r] = v1.z; Xs[kb+ 7][r] = v1.w;
            Xs[kb+ 8][r] = v2.x; Xs[kb+ 9][r] = v2.y; Xs[kb+10][r] = v2.z; Xs[kb+11][r] = v2.w;
            Xs[kb+12][r] = v3.x; Xs[kb+13][r] = v3.y; Xs[kb+14][r] = v3.z; Xs[kb+15][r] = v3.w;
        }
        {
            int kr = t >> 3;               // 0..31
            int cc = (t & 7) * 16;         // 0..112
            const float* p = W + (size_t)(k0 + kr) * 128 + cc;
            float4 w0 = ((const float4*)p)[0];
            float4 w1 = ((const float4*)p)[1];
            float4 w2 = ((const float4*)p)[2];
            float4 w3 = ((const float4*)p)[3];
            *(float4*)&Ws[kr][cc + 0]  = w0;
            *(float4*)&Ws[kr][cc + 4]  = w1;
            *(float4*)&Ws[kr][cc + 8]  = w2;
            *(float4*)&Ws[kr][cc + 12] = w3;
        }
        __syncthreads();
#pragma unroll
        for (int kk = 0; kk < GBK; ++kk) {
            float4 a0 = *(const float4*)&Xs[kk][row0];
            float4 a1 = *(const float4*)&Xs[kk][row0 + 4];
            float4 w0 = *(const float4*)&Ws[kk][col0];
            float4 w1 = *(const float4*)&Ws[kk][col0 + 4];
            float av[8] = {a0.x, a0.y, a0.z, a0.w, a1.x, a1.y, a1.z, a1.w};
            float wv[8] = {w0.x, w0.y, w0.z, w0.w, w1.x, w1.y, w1.z, w1.w};
#pragma unroll
            for (int i = 0; i < 8; ++i)
#pragma unroll
                for (int j = 0; j < 8; ++j)
                    acc[i][j] = fmaf(av[i], wv[j], acc[i][j]);
        }
        __syncthreads();
    }

    int cg = t & 15;
    int head = cg >> 2;                       // col0/32
    const float* asrc = avs + head * 32 + (cg & 3) * 8;
    const float* adst = avd + head * 32 + (cg & 3) * 8;
#pragma unroll
    for (int i = 0; i < 8; ++i) {
        int grow = block_row + row0 + i;
        bool ok = (grow < nrows);
        if (ok) {
            float4 o0 = make_float4(acc[i][0], acc[i][1], acc[i][2], acc[i][3]);
            float4 o1 = make_float4(acc[i][4], acc[i][5], acc[i][6], acc[i][7]);
            *(float4*)&Hh[(size_t)grow * 128 + col0]     = o0;
            *(float4*)&Hh[(size_t)grow * 128 + col0 + 4] = o1;
        }
        float ps = 0.f, pd = 0.f;
#pragma unroll
        for (int j = 0; j < 8; ++j) {
            ps = fmaf(acc[i][j], asrc[j], ps);
            pd = fmaf(acc[i][j], adst[j], pd);
        }
        ps += __shfl_xor(ps, 1); ps += __shfl_xor(ps, 2);
        pd += __shfl_xor(pd, 1); pd += __shfl_xor(pd, 2);
        if (ok && (cg & 3) == 0) {
            alpha_s[grow * 4 + head] = ps;
            alpha_d[grow * 4 + head] = pd;
        }
    }
}

// ------- fused attention + gather, SINGLE PASS, no LDS --------------------
// out = elu( (sum_e ex_e * h[src_e]) / (sum_e ex_e) + b ),
// ex_e = exp(leakyrelu(alpha_s[src_e] + alpha_d[node]))  (no max-shift:
// logits are O(+-6), exp fp32-safe, softmax shift-invariant).
// One wave per node. half = lane>>5 handles edges of parity `half`;
// lane owns features q*4..q*4+3 (q = lane&31, head hh = q>>3): 32 lanes x
// 16B = full 512B h row per edge. Each lane computes its own ex inline
// (8x redundant exp, ~5us total VALU) -> no LDS handoff, no phase barrier,
// independent iterations the compiler can pipeline. den accumulated
// alongside; both combined with one shfl_xor(32); normalize at the end.
__global__ __launch_bounds__(256) void att_gather_kernel(
    const int* __restrict__ csr_src, const int* __restrict__ roff,
    const float* __restrict__ alpha_s, const float* __restrict__ alpha_d,
    const float* __restrict__ hbuf, const float* __restrict__ b,
    float* __restrict__ out)
{
    int node = blockIdx.x * 4 + (threadIdx.x >> 6);
    if (node >= NNODES) return;
    int lane = threadIdx.x & 63;
    int half = lane >> 5;               // edge parity this lane handles
    int q    = lane & 31;
    int f    = q * 4;                   // features f..f+3
    int hh   = q >> 3;                  // head owning features f..f+3
    int beg = roff[node], end = roff[node + 1];
    float ad = alpha_d[node * 4 + hh];

    float4 a4 = make_float4(0.f, 0.f, 0.f, 0.f);
    float den = 0.f;
    int i = beg + half;
    for (; i + 2 < end; i += 4) {       // 2 independent edges per lane/iter
        int s0 = csr_src[i];
        int s1 = csr_src[i + 2];
        float l0 = alpha_s[s0 * 4 + hh] + ad;
        float l1 = alpha_s[s1 * 4 + hh] + ad;
        l0 = (l0 >= 0.f) ? l0 : 0.2f * l0;
        l1 = (l1 >= 0.f) ? l1 : 0.2f * l1;
        float e0 = __expf(l0);
        float e1 = __expf(l1);
        float4 h0 = *(const float4*)(hbuf + (size_t)s0 * 128 + f);
        float4 h1 = *(const float4*)(hbuf + (size_t)s1 * 128 + f);
        den += e0 + e1;
        a4.x = fmaf(e0, h0.x, a4.x); a4.y = fmaf(e0, h0.y, a4.y);
        a4.z = fmaf(e0, h0.z, a4.z); a4.w = fmaf(e0, h0.w, a4.w);
        a4.x = fmaf(e1, h1.x, a4.x); a4.y = fmaf(e1, h1.y, a4.y);
        a4.z = fmaf(e1, h1.z, a4.z); a4.w = fmaf(e1, h1.w, a4.w);
    }
    if (i < end) {
        int s0 = csr_src[i];
        float l0 = alpha_s[s0 * 4 + hh] + ad;
        l0 = (l0 >= 0.f) ? l0 : 0.2f * l0;
        float e0 = __expf(l0);
        float4 h0 = *(const float4*)(hbuf + (size_t)s0 * 128 + f);
        den += e0;
        a4.x = fmaf(e0, h0.x, a4.x); a4.y = fmaf(e0, h0.y, a4.y);
        a4.z = fmaf(e0, h0.z, a4.z); a4.w = fmaf(e0, h0.w, a4.w);
    }

    // combine even/odd halves (lane l and l+32 hold the same features/head)
    a4.x += __shfl_xor(a4.x, 32);
    a4.y += __shfl_xor(a4.y, 32);
    a4.z += __shfl_xor(a4.z, 32);
    a4.w += __shfl_xor(a4.w, 32);
    den  += __shfl_xor(den, 32);

    if (half == 0) {
        float rd = 1.f / fmaxf(den, 1e-16f);
        float4 bv = *(const float4*)(b + f);
        float x0 = a4.x * rd + bv.x;
        float x1 = a4.y * rd + bv.y;
        float x2 = a4.z * rd + bv.z;
        float x3 = a4.w * rd + bv.w;
        x0 = (x0 > 0.f) ? x0 : expm1f(x0);
        x1 = (x1 > 0.f) ? x1 : expm1f(x1);
        x2 = (x2 > 0.f) ? x2 : expm1f(x2);
        x3 = (x3 > 0.f) ? x3 : expm1f(x3);
        *(float4*)(out + (size_t)node * 128 + f) = make_float4(x0, x1, x2, x3);
    }
}

extern "C" void kernel_launch(void* const* d_in, const int* in_sizes, int n_in,
                              void* d_out, int out_size, void* d_ws, size_t ws_size,
                              hipStream_t stream) {
    const float* X    = (const float*)d_in[0];
    const int*   ei   = (const int*)d_in[1];
    const float* W0   = (const float*)d_in[2];
    const float* as0  = (const float*)d_in[3];
    const float* ad0  = (const float*)d_in[4];
    const float* b0   = (const float*)d_in[5];
    const float* W1   = (const float*)d_in[6];
    const float* as1  = (const float*)d_in[7];
    const float* ad1  = (const float*)d_in[8];
    const float* b1   = (const float*)d_in[9];

    const int* srcp = ei;            // edge_index[0]
    const int* dstp = ei + NEDGES;   // edge_index[1]

    float* ws = (float*)d_ws;
    float* h    = ws;                        // 6,400,000 floats
    float* hout = h    + 6400000;            // 6,400,000
    float* as_  = hout + 6400000;            // 200,000
    float* ad_  = as_  + 200000;             // 200,000
    int*   deg     = (int*)(ad_ + 200000);   // 50,000 ints
    int*   roff    = deg + 50000;            // 50,001
    int*   cursor  = roff + 50001;           // 50,000
    int*   csr_src = cursor + 50000;         // 800,000
    int*   bsum    = csr_src + 800000;       // 196
    int*   boff    = bsum + NSCANB;          // 196

    // ---- CSR build (by destination), layer-invariant ----
    hipMemsetAsync(deg, 0, NNODES * sizeof(int), stream);
    hist_kernel<<<(NEDGES + 255) / 256, 256, 0, stream>>>(dstp, deg);
    scan1_kernel<<<NSCANB, 256, 0, stream>>>(deg, bsum);
    scan2_kernel<<<1, 256, 0, stream>>>(bsum, boff, roff);
    scan3_kernel<<<NSCANB, 256, 0, stream>>>(deg, boff, roff, cursor);
    bucket_kernel<<<(NEDGES + 255) / 256, 256, 0, stream>>>(srcp, dstp, cursor, csr_src);

    const int NODE_BLOCKS = (NNODES + 3) / 4;   // 4 nodes (waves) per block

    for (int layer = 0; layer < 2; ++layer) {
        const float* Hin = layer ? hout : X;
        const float* W   = layer ? W1  : W0;
        const float* avs = layer ? as1 : as0;
        const float* avd = layer ? ad1 : ad0;
        const float* bv  = layer ? b1  : b0;
        float* outp      = layer ? (float*)d_out : hout;

        gemm_alpha_kernel<<<(NNODES + GBM - 1) / GBM, 256, 0, stream>>>(
            Hin, W, avs, avd, h, as_, ad_, NNODES);

        att_gather_kernel<<<NODE_BLOCKS, 256, 0, stream>>>(
            csr_src, roff, as_, ad_, h, bv, outp);
    }
}